// Round 1
// baseline (321.848 us; speedup 1.0000x reference)
//
#include <hip/hip_runtime.h>
#include <hip/hip_bf16.h>

// GraphSAGE 3-layer inference, MI355X.
// Shapes: x[256000,1024] f32; nbr0[25600,10], nbr1[2560,10], nbr2[512,5] i32;
// W*0 [1024,256], W*1 [256,256], W*2 [256,19] f32; out [512,19] f32.
//
// Pipeline:
//   gather_cat<1024,10>: A0[i] = [bf16(x[i]) | bf16(mean_f x[nbr0[i,f]])]  (25600 x 2048)
//   gemm_bf16          : h0 = relu(A0 @ Wt0^T + b0)                        (25600 x 256, f32)
//   gather_cat<256,10> : cat1 (2560 x 512 bf16)
//   gemm_bf16          : h1 = relu(cat1 @ Wt1^T + b1)                      (2560 x 256, f32)
//   gather_cat<256,5>  : cat2 (512 x 512 bf16)
//   out_layer          : out = cat2 @ [Ws2;Wn2] + b2                       (512 x 19, f32)

typedef __attribute__((ext_vector_type(4))) float f32x4;
typedef __attribute__((ext_vector_type(8))) short s16x8;

__device__ __forceinline__ unsigned short f2bf_u16(float f) {
  // round-to-nearest-even f32 -> bf16 (finite inputs only)
  unsigned int u = __float_as_uint(f);
  u += 0x7fffu + ((u >> 16) & 1u);
  return (unsigned short)(u >> 16);
}

__device__ __forceinline__ float bf2f(unsigned short u) {
  return __uint_as_float(((unsigned int)u) << 16);
}

// Build Wt[n][k] = bf16( k<Khalf ? Wself[k][n] : Wneigh[k-Khalf][n] ), n in [0,N)
__global__ void prep_wcat(const float* __restrict__ Wself,
                          const float* __restrict__ Wneigh,
                          unsigned short* __restrict__ Wt, int Khalf, int N) {
  int idx = blockIdx.x * 256 + threadIdx.x;
  int Kc = 2 * Khalf;
  if (idx >= N * Kc) return;
  int n = idx / Kc, k = idx - n * Kc;
  float v = (k < Khalf) ? Wself[(size_t)k * N + n] : Wneigh[(size_t)(k - Khalf) * N + n];
  Wt[idx] = f2bf_u16(v);
}

// One block per dst node; blockDim.x == D/4 exactly.
// out row (2*D bf16) = [ self | mean over F sampled neighbors ]
template <int D, int F>
__global__ void gather_cat(const float* __restrict__ h,
                           const int* __restrict__ nbr,
                           unsigned short* __restrict__ out) {
  const int i = blockIdx.x;
  const int c = threadIdx.x;  // float4 slot
  int idx[F];
#pragma unroll
  for (int f = 0; f < F; ++f) idx[f] = nbr[(size_t)i * F + f];
  constexpr float inv = 1.0f / (float)F;

  float4 s = reinterpret_cast<const float4*>(h + (size_t)i * D)[c];
  ushort4 us = {f2bf_u16(s.x), f2bf_u16(s.y), f2bf_u16(s.z), f2bf_u16(s.w)};
  reinterpret_cast<ushort4*>(out + (size_t)i * 2 * D)[c] = us;

  float ax = 0.f, ay = 0.f, az = 0.f, aw = 0.f;
#pragma unroll
  for (int f = 0; f < F; ++f) {
    float4 v = reinterpret_cast<const float4*>(h + (size_t)idx[f] * D)[c];
    ax += v.x; ay += v.y; az += v.z; aw += v.w;
  }
  ushort4 un = {f2bf_u16(ax * inv), f2bf_u16(ay * inv), f2bf_u16(az * inv), f2bf_u16(aw * inv)};
  reinterpret_cast<ushort4*>(out + (size_t)i * 2 * D + D)[c] = un;
}

// C[m][n] = sum_k A[m][k] * Bt[n][k]  (+bias, optional relu)
// A: [M][Kc] bf16 row-major, Bt: [N][Kc] bf16 row-major (pre-transposed weights).
// mfma_f32_16x16x32_bf16; A-frag: row=lane&15, k=8*(lane>>4)+j;
// C/D: col=lane&15, row=(lane>>4)*4+r  [per guide, m89-verified].
template <int BM, int BN, int WM, int WN, bool RELU>
__global__ void gemm_bf16(const unsigned short* __restrict__ A,
                          const unsigned short* __restrict__ Bt,
                          const float* __restrict__ bias,
                          float* __restrict__ C,
                          int M, int N, int Kc) {
  constexpr int BK = 32;
  constexpr int LDK = BK + 8;  // +8 bf16 pad -> row stride 80B, ~2-way conflict max
  constexpr int THREADS = WM * WN * 64;
  constexpr int MF = BM / (WM * 16);
  constexpr int NF = BN / (WN * 16);
  __shared__ __align__(16) unsigned short As[BM][LDK];
  __shared__ __align__(16) unsigned short Bs[BN][LDK];

  const int tid = threadIdx.x;
  const int wid = tid >> 6, lane = tid & 63;
  const int wm = wid / WN, wn = wid % WN;
  const size_t bm = (size_t)blockIdx.x * BM;
  const size_t bn = (size_t)blockIdx.y * BN;

  f32x4 acc[MF][NF];
#pragma unroll
  for (int mi = 0; mi < MF; ++mi)
#pragma unroll
    for (int ni = 0; ni < NF; ++ni)
      acc[mi][ni] = (f32x4){0.f, 0.f, 0.f, 0.f};

  const int arow = tid >> 2;           // THREADS/4 rows per pass
  const int apart = (tid & 3) * 8;     // 8 bf16 = 16B per thread
  const int klo = (lane >> 4) * 8;
  const int l15 = lane & 15;

  for (int kt = 0; kt < Kc; kt += BK) {
#pragma unroll
    for (int r = 0; r < BM; r += THREADS / 4) {
      s16x8 v = *reinterpret_cast<const s16x8*>(A + (bm + r + arow) * (size_t)Kc + kt + apart);
      *reinterpret_cast<s16x8*>(&As[r + arow][apart]) = v;
    }
#pragma unroll
    for (int r = 0; r < BN; r += THREADS / 4) {
      s16x8 v = *reinterpret_cast<const s16x8*>(Bt + (bn + r + arow) * (size_t)Kc + kt + apart);
      *reinterpret_cast<s16x8*>(&Bs[r + arow][apart]) = v;
    }
    __syncthreads();

    s16x8 af[MF], bfr[NF];
#pragma unroll
    for (int mi = 0; mi < MF; ++mi)
      af[mi] = *reinterpret_cast<const s16x8*>(&As[wm * MF * 16 + mi * 16 + l15][klo]);
#pragma unroll
    for (int ni = 0; ni < NF; ++ni)
      bfr[ni] = *reinterpret_cast<const s16x8*>(&Bs[wn * NF * 16 + ni * 16 + l15][klo]);
#pragma unroll
    for (int mi = 0; mi < MF; ++mi)
#pragma unroll
      for (int ni = 0; ni < NF; ++ni)
        acc[mi][ni] = __builtin_amdgcn_mfma_f32_16x16x32_bf16(af[mi], bfr[ni], acc[mi][ni], 0, 0, 0);
    __syncthreads();
  }

  const int rif = (lane >> 4) * 4;
#pragma unroll
  for (int mi = 0; mi < MF; ++mi) {
    size_t r0 = bm + wm * MF * 16 + mi * 16 + rif;
#pragma unroll
    for (int ni = 0; ni < NF; ++ni) {
      int c = (int)bn + wn * NF * 16 + ni * 16 + l15;
      float bv = bias[c];
#pragma unroll
      for (int r = 0; r < 4; ++r) {
        float v = acc[mi][ni][r] + bv;
        if (RELU) v = fmaxf(v, 0.f);
        C[(r0 + r) * (size_t)N + c] = v;
      }
    }
  }
}

// Final layer: out[i][n] = sum_k cat[i][k] * Wcat[k][n] + b[n], K=512, N=19. One block per row.
__global__ void out_layer(const unsigned short* __restrict__ cat,
                          const float* __restrict__ Ws, const float* __restrict__ Wn,
                          const float* __restrict__ b, float* __restrict__ out) {
  const int i = blockIdx.x, t = threadIdx.x;  // 256 threads
  __shared__ float row[512];
  __shared__ float part[8][32];
  row[t]       = bf2f(cat[(size_t)i * 512 + t]);
  row[t + 256] = bf2f(cat[(size_t)i * 512 + t + 256]);
  __syncthreads();
  const int n = t & 31, seg = t >> 5;  // 8 segments x 64 k-elems
  float p = 0.f;
  if (n < 19) {
#pragma unroll
    for (int e = 0; e < 64; ++e) {
      int k = seg * 64 + e;
      float w = (k < 256) ? Ws[k * 19 + n] : Wn[(k - 256) * 19 + n];
      p += row[k] * w;
    }
  }
  part[seg][n] = p;
  __syncthreads();
  if (t < 19) {
    float s = b[t];
#pragma unroll
    for (int g = 0; g < 8; ++g) s += part[g][t];
    out[(size_t)i * 19 + t] = s;
  }
}

extern "C" void kernel_launch(void* const* d_in, const int* in_sizes, int n_in,
                              void* d_out, int out_size, void* d_ws, size_t ws_size,
                              hipStream_t stream) {
  const float* x   = (const float*)d_in[0];
  const int*   nbr0 = (const int*)d_in[1];
  const int*   nbr1 = (const int*)d_in[2];
  const int*   nbr2 = (const int*)d_in[3];
  const float* Ws0 = (const float*)d_in[4];
  const float* Wn0 = (const float*)d_in[5];
  const float* b0  = (const float*)d_in[6];
  const float* Ws1 = (const float*)d_in[7];
  const float* Wn1 = (const float*)d_in[8];
  const float* b1  = (const float*)d_in[9];
  const float* Ws2 = (const float*)d_in[10];
  const float* Wn2 = (const float*)d_in[11];
  const float* b2  = (const float*)d_in[12];
  float* out = (float*)d_out;

  char* ws = (char*)d_ws;
  unsigned short* A0   = (unsigned short*)(ws);                 // 25600*2048*2 = 104857600
  unsigned short* Wt0  = (unsigned short*)(ws + 104857600);     // 256*2048*2   =   1048576
  float*          h0   = (float*)(ws + 105906176);              // 25600*256*4  =  26214400
  unsigned short* cat1 = (unsigned short*)(ws + 132120576);     // 2560*512*2   =   2621440
  unsigned short* Wt1  = (unsigned short*)(ws + 134742016);     // 256*512*2    =    262144
  float*          h1   = (float*)(ws + 135004160);              // 2560*256*4   =   2621440
  unsigned short* cat2 = (unsigned short*)(ws + 137625600);     // 512*512*2    =    524288
  // total ws use: 138149888 bytes

  prep_wcat<<<(256 * 2048 + 255) / 256, 256, 0, stream>>>(Ws0, Wn0, Wt0, 1024, 256);
  prep_wcat<<<(256 * 512 + 255) / 256, 256, 0, stream>>>(Ws1, Wn1, Wt1, 256, 256);

  gather_cat<1024, 10><<<25600, 256, 0, stream>>>(x, nbr0, A0);
  gemm_bf16<128, 256, 2, 4, true>
      <<<dim3(200, 1), 512, 0, stream>>>(A0, Wt0, b0, h0, 25600, 256, 2048);

  gather_cat<256, 10><<<2560, 64, 0, stream>>>(h0, nbr1, cat1);
  gemm_bf16<64, 128, 2, 2, true>
      <<<dim3(40, 2), 256, 0, stream>>>(cat1, Wt1, b1, h1, 2560, 256, 512);

  gather_cat<256, 5><<<512, 64, 0, stream>>>(h1, nbr2, cat2);
  out_layer<<<512, 256, 0, stream>>>(cat2, Ws2, Wn2, b2, out);
}